// Round 9
// baseline (444.408 us; speedup 1.0000x reference)
//
#include <hip/hip_runtime.h>
#include <math.h>

#define BETA_C   0.99f
#define TOL_C    1e-4f
#define ACC_C    1e-3f   // early-accept: secant step smaller than this -> done
#define BRK_C    1e-3f   // bracket-width accept (same accuracy class as ACC_C)
#define FORCE_C  6       // secant gets 6 tries, then pure bisection
#define MAXIT_C  1000
#define EPS_C    1e-3f
#define BN       65536
#define NN       32
#define HFD      25
#define HVD      128
#define KVD      8
#define G        16   // lanes per cooperative group
#define GPB      16   // groups per 256-thread block (k_setup; 2 samples/group)
#define SGPB     16   // groups per 256-thread solver block
#define SBLK     256  // solver block threads
#define NQBLK    1024 // solver blocks (4 resident/CU at 40KB LDS = all resident)

typedef __attribute__((ext_vector_type(8))) short bf16x8;  // 8 bf16 (4 VGPRs)
typedef __attribute__((ext_vector_type(8))) unsigned short u16x8;
typedef __attribute__((ext_vector_type(4))) float f32x4;   // 4 fp32 acc

// wave-internal LDS ordering (groups live inside one wave; no block barrier
// inside the divergent solve loop).
__device__ __forceinline__ void wsync() {
    __builtin_amdgcn_wave_barrier();
    __threadfence_block();
    __builtin_amdgcn_wave_barrier();
}

__device__ __forceinline__ float sp_(float x) {
    return fmaxf(x, 0.f) + log1pf(expf(-fabsf(x)));
}
// fast softplus: __expf/__logf (rel err ~1e-6; negligible vs TOL / bf16 budget)
__device__ __forceinline__ float spf_(float x) {
    return fmaxf(x, 0.f) + __logf(1.f + __expf(-fabsf(x)));
}
__device__ __forceinline__ float sgn_(float d) {
    return (d > 0.f) ? 1.f : ((d < 0.f) ? -1.f : 0.f);
}
__device__ __forceinline__ unsigned short f2bf(float f) {   // RNE f32->bf16
    unsigned int u = __float_as_uint(f);
    u += 0x7FFFu + ((u >> 16) & 1u);
    return (unsigned short)(u >> 16);
}
__device__ __forceinline__ float bf2f(unsigned short u) {
    return __uint_as_float(((unsigned int)u) << 16);
}

// ---- swizzled per-wave LDS activation tiles (G4: XOR row bits into bank bits)
__device__ __forceinline__ void aw_st(unsigned short* aw, int row, int col, float v) {
    const int b = (row * 64 + col * 2) ^ ((row & 3) << 4);
    *(unsigned short*)((char*)aw + b) = f2bf(v);
}
__device__ __forceinline__ bf16x8 aw_ld(const unsigned short* aw, int row, int k) {
    const int b = (row * 64 + k * 2) ^ ((row & 3) << 4);
    return *(const bf16x8*)((const char*)aw + b);
}
__device__ __forceinline__ void hw_st(unsigned short* hw, int row, int col, float v) {
    const int b = (row * 256 + col * 2) ^ ((row & 7) << 4);
    *(unsigned short*)((char*)hw + b) = f2bf(v);
}
__device__ __forceinline__ bf16x8 hw_ld(const unsigned short* hw, int row, int k) {
    const int b = (row * 256 + k * 2) ^ ((row & 7) << 4);
    return *(const bf16x8*)((const char*)hw + b);
}

// ---------------------------------------------------------------------------
// paired V-ONLY eval (k_solve, secant solver): V(fxA*gA), V(fxB*gB), sharing
// all W2 loads from LDS.  R9 LDS diet: h1 stored as packed 2xbf16 (u32) —
// same precision class as k_setup's bf16-MFMA h1, so tgt consistency is
// unchanged; w3 reads go to global w3s (2KB, L1-resident now that W2 no
// longer streams through L1).  h1 store index swizzle (j<<4)|gl: 4-way bank
// conflict instead of 16-way; reads are uniform (broadcast, free).
__device__ __forceinline__ void veval2_sec(
    const int gl, const float (&uA)[8], const float (&uB)[8],
    const float gA, const float gB,
    unsigned* h1q, const float n2A, const float n2B,
    const float (&b1v)[8], const float (&b2v)[8], const float (&d0c)[8],
    const unsigned short* w2L, const unsigned short* __restrict__ w3s,
    float& VA, float& VB)
{
    const int k0 = gl * 8;
#pragma unroll
    for (int j = 0; j < 8; ++j) {
        const float preA = fmaf(gA, uA[j], b1v[j]);
        const float preB = fmaf(gB, uB[j], b1v[j]);
        const unsigned pa = f2bf(spf_(preA));
        const unsigned pb = f2bf(spf_(preB));
        h1q[(j << 4) | gl] = pa | (pb << 16);   // swizzled store (k=gl*8+j)
    }
    wsync();
    float aA[8], aB[8];
#pragma unroll
    for (int j = 0; j < 8; ++j) { aA[j] = 0.f; aB[j] = 0.f; }
#pragma unroll 4
    for (int k = 0; k < HVD; ++k) {
        const unsigned hp = h1q[((k & 7) << 4) | (k >> 3)];   // uniform -> broadcast
        const float qx = bf2f((unsigned short)(hp & 0xffffu));
        const float qy = bf2f((unsigned short)(hp >> 16));
        const u16x8 wv = *(const u16x8*)(w2L + k * HVD + k0);  // ds_read_b128
#pragma unroll
        for (int j = 0; j < 8; ++j) {
            const float w = bf2f(wv[j]);
            aA[j] = fmaf(qx, w, aA[j]);
            aB[j] = fmaf(qy, w, aB[j]);
        }
    }
    wsync();
    float oA[KVD], oB[KVD];
#pragma unroll
    for (int c = 0; c < KVD; ++c) { oA[c] = 0.f; oB[c] = 0.f; }
#pragma unroll
    for (int j = 0; j < 8; ++j) {
        const float h2A = spf_(aA[j] + b2v[j]);
        const float h2B = spf_(aB[j] + b2v[j]);
        const u16x8 w3v = *(const u16x8*)(w3s + (k0 + j) * KVD);   // global, L1
#pragma unroll
        for (int c = 0; c < 8; ++c) {
            const float w3 = bf2f(w3v[c]);
            oA[c] = fmaf(h2A, w3, oA[c]);
            oB[c] = fmaf(h2B, w3, oB[c]);
        }
    }
#pragma unroll
    for (int m = 1; m < G; m <<= 1) {
#pragma unroll
        for (int c = 0; c < KVD; ++c) {
            oA[c] += __shfl_xor(oA[c], m);
            oB[c] += __shfl_xor(oB[c], m);
        }
    }
    float vvA = 0.f, vvB = 0.f;
#pragma unroll
    for (int c = 0; c < KVD; ++c) {
        const float eA = oA[c] + d0c[c];
        const float eB = oB[c] + d0c[c];
        vvA = fmaf(eA, eA, vvA);
        vvB = fmaf(eB, eB, vvB);
    }
    VA = vvA + EPS_C * gA * gA * n2A;
    VB = vvB + EPS_C * gB * gB * n2B;
}

// ---- h0 = V-MLP(0) : weight-only, one tiny block --------------------------
__global__ __launch_bounds__(128) void k_h0(
    const float* __restrict__ vb1, const float* __restrict__ vW2,
    const float* __restrict__ vb2, const float* __restrict__ vW3,
    const float* __restrict__ vb3, float* __restrict__ h0g)
{
    __shared__ float h1s[HVD];
    __shared__ float h2s[HVD];
    int j = threadIdx.x;
    h1s[j] = sp_(vb1[j]);
    __syncthreads();
    float a = vb2[j];
    for (int k = 0; k < HVD; ++k) a = fmaf(h1s[k], vW2[k * HVD + j], a);
    h2s[j] = sp_(a);
    __syncthreads();
    if (j < KVD) {
        float acc = vb3[j];
        for (int k = 0; k < HVD; ++k) acc = fmaf(h2s[k], vW3[k * KVD + j], acc);
        h0g[j] = acc;
    }
}

// ---- weight prep: V-net weights -> bf16 ------------------------------------
__global__ __launch_bounds__(256) void k_wprep(
    const float* __restrict__ vW1, const float* __restrict__ vW2,
    const float* __restrict__ vW3,
    unsigned short* __restrict__ w1b, unsigned short* __restrict__ w2b,
    unsigned short* __restrict__ w3b,
    unsigned short* __restrict__ w2s, unsigned short* __restrict__ w3s)
{
    const int t = blockIdx.x * 256 + threadIdx.x;
    const int nth = gridDim.x * 256;
    for (int i = t; i < HVD * NN; i += nth) {          // [128 col][32 k]
        const int col = i >> 5, k = i & 31;
        w1b[i] = f2bf(vW1[k * HVD + col]);
    }
    for (int i = t; i < HVD * HVD; i += nth) {         // [128 col][128 k]
        const int col = i >> 7, k = i & 127;
        w2b[i] = f2bf(vW2[k * HVD + col]);
    }
    for (int i = t; i < 16 * HVD; i += nth) {          // [16 col][128 k], cols 8..15 = 0
        const int c = i >> 7, k = i & 127;
        w3b[i] = (c < KVD) ? f2bf(vW3[k * KVD + c]) : (unsigned short)0;
    }
    for (int i = t; i < HVD * HVD; i += nth)           // [k][col] elementwise
        w2s[i] = f2bf(vW2[i]);
    for (int i = t; i < HVD * KVD; i += nth)           // [k][c] elementwise
        w3s[i] = f2bf(vW3[i]);
}

// ---- setup: f-net fp32 (spf_ softplus), V-net via bf16 MFMA ---------------
// R9: f-net processes BOTH samples in one pass (2-way ILP on the dependent
// fma chains + shared fW loads; per-sample accumulation order unchanged ->
// bit-identical results, just time-interleaved).
__global__ __launch_bounds__(256, 4) void k_setup(
    const float* __restrict__ x_g,
    const float* __restrict__ fW1, const float* __restrict__ fb1,
    const float* __restrict__ fW2, const float* __restrict__ fb2,
    const float* __restrict__ fW3, const float* __restrict__ fb3,
    const float* __restrict__ vb1, const float* __restrict__ vb2,
    const float* __restrict__ vb3,
    const unsigned short* __restrict__ w1b,
    const unsigned short* __restrict__ w2b,
    const unsigned short* __restrict__ w3b,
    const float* __restrict__ h0g,
    float* __restrict__ out,
    int* __restrict__ cnt, int* __restrict__ list, float* __restrict__ tgt,
    float* __restrict__ vfb)
{
    __shared__ float2 xs[GPB][NN + 1];                       // 4.2 KB (f-net x)
    __shared__ float2 fh1[GPB][HFD + 1];                     // 3.3 KB (A,B pair)
    __shared__ float2 fh2[GPB][HFD + 1];                     // 3.3 KB
    __shared__ __align__(16) unsigned short abf[4][16 * 32]; // 4 KB  (Z rows bf16)
    __shared__ __align__(16) unsigned short hbf[4][16 * HVD];// 16 KB (h1/h2 reuse)
    __shared__ int wcnt[4];
    __shared__ int bbase;

    const int tid = threadIdx.x;
    const int gi = tid >> 4;          // group 0..15
    const int gl = tid & (G - 1);
    const int w  = tid >> 6;          // wave 0..3
    const int l  = tid & 63;
    const int q  = l >> 4;            // lane quad within wave (== gi & 3)
    const int cc = l & 15;
    const int sb = (blockIdx.x * GPB + gi) * 2;
    const int s0 = sb, s1 = sb + 1;
    unsigned short* aw = abf[w];
    unsigned short* hw = hbf[w];

    // ---- stage x (fp32 for f-net, bf16 rows for V A-operand) ----
    const float xa0 = x_g[(size_t)s0 * NN + gl];
    const float xa1 = x_g[(size_t)s0 * NN + gl + 16];
    const float xb0 = x_g[(size_t)s1 * NN + gl];
    const float xb1 = x_g[(size_t)s1 * NN + gl + 16];
    xs[gi][gl]      = make_float2(xa0, xb0);
    xs[gi][gl + 16] = make_float2(xa1, xb1);
    const int r0 = 4 * q;             // this group's base row in the wave tile
    aw_st(aw, r0,     gl,      xa0); aw_st(aw, r0,     gl + 16, xa1);
    aw_st(aw, r0 + 2, gl,      xb0); aw_st(aw, r0 + 2, gl + 16, xb1);
    wsync();

    // ---- f-net, both samples interleaved (fp32 fma, fast softplus) ----
    float fA0, fA1, fB0, fB1;
    for (int uu = gl; uu < HFD; uu += G) {
        float a0 = fb1[uu];
        float a1 = a0;
#pragma unroll
        for (int i = 0; i < NN; ++i) {
            const float2 xv2 = xs[gi][i];
            const float wv = fW1[i * HFD + uu];
            a0 = fmaf(xv2.x, wv, a0);
            a1 = fmaf(xv2.y, wv, a1);
        }
        fh1[gi][uu] = make_float2(spf_(a0), spf_(a1));
    }
    wsync();
    for (int uu = gl; uu < HFD; uu += G) {
        float a0 = fb2[uu];
        float a1 = a0;
#pragma unroll
        for (int i = 0; i < HFD; ++i) {
            const float2 h = fh1[gi][i];
            const float wv = fW2[i * HFD + uu];
            a0 = fmaf(h.x, wv, a0);
            a1 = fmaf(h.y, wv, a1);
        }
        fh2[gi][uu] = make_float2(spf_(a0), spf_(a1));
    }
    wsync();
    {
        float A0 = fb3[gl], A1 = fb3[gl + 16];
        float B0 = A0,      B1 = A1;
#pragma unroll
        for (int i = 0; i < HFD; ++i) {
            const float2 h = fh2[gi][i];
            const float wa = fW3[i * NN + gl];
            const float wb = fW3[i * NN + gl + 16];
            A0 = fmaf(h.x, wa, A0); A1 = fmaf(h.x, wb, A1);
            B0 = fmaf(h.y, wa, B0); B1 = fmaf(h.y, wb, B1);
        }
        out[(size_t)s0 * NN + gl]      = A0;
        out[(size_t)s0 * NN + gl + 16] = A1;
        out[(size_t)s1 * NN + gl]      = B0;
        out[(size_t)s1 * NN + gl + 16] = B1;
        aw_st(aw, r0 + 1, gl, A0); aw_st(aw, r0 + 1, gl + 16, A1);
        aw_st(aw, r0 + 3, gl, B0); aw_st(aw, r0 + 3, gl + 16, B1);
        fA0 = A0; fA1 = A1; fB0 = B0; fB1 = B1;
    }
    wsync();

    // ---- ||z||^2 per row (fp32 exact) ----
    float p0 = fmaf(xa0, xa0, xa1 * xa1);
    float p1 = fmaf(fA0, fA0, fA1 * fA1);
    float p2 = fmaf(xb0, xb0, xb1 * xb1);
    float p3 = fmaf(fB0, fB0, fB1 * fB1);
#pragma unroll
    for (int m = 1; m < G; m <<= 1) {
        p0 += __shfl_xor(p0, m); p1 += __shfl_xor(p1, m);
        p2 += __shfl_xor(p2, m); p3 += __shfl_xor(p3, m);
    }

    float b1v[8], b2v[8];
#pragma unroll
    for (int n = 0; n < 8; ++n) {
        b1v[n] = vb1[n * 16 + cc];    // col = n*16 + cc
        b2v[n] = vb2[n * 16 + cc];
    }

    const int kq = (l >> 4) * 8;      // this lane's k-offset within a K=32 chunk
    const f32x4 zf = {0.f, 0.f, 0.f, 0.f};

    // ---- V layer 1: u[16][128] = Z[16][32] @ W1  (8 MFMA, K=32 exact) ----
    const bf16x8 afr = aw_ld(aw, cc, kq);        // A: row=l&15, k=8*(l>>4)+j
    f32x4 acc1[8];
#pragma unroll
    for (int n = 0; n < 8; ++n) {
        const bf16x8 bfr = *(const bf16x8*)(w1b + (n * 16 + cc) * 32 + kq);
        acc1[n] = __builtin_amdgcn_mfma_f32_16x16x32_bf16(afr, bfr, zf, 0, 0, 0);
    }
    // h1 = softplus(u + b1) -> hbf (C layout: row=4q+r, col=n*16+cc)
#pragma unroll
    for (int n = 0; n < 8; ++n) {
#pragma unroll
        for (int r = 0; r < 4; ++r)
            hw_st(hw, r0 + r, n * 16 + cc, spf_(acc1[n][r] + b1v[n]));
    }
    wsync();

    // ---- V layer 2: a2[16][128] = H1 @ W2  (32 MFMA) ----
    f32x4 acc2[8];
#pragma unroll
    for (int n = 0; n < 8; ++n) acc2[n] = zf;
#pragma unroll
    for (int c = 0; c < 4; ++c) {
        const bf16x8 a2f = hw_ld(hw, cc, c * 32 + kq);
#pragma unroll
        for (int n = 0; n < 8; ++n) {
            const bf16x8 b2f = *(const bf16x8*)(w2b + (n * 16 + cc) * HVD + c * 32 + kq);
            acc2[n] = __builtin_amdgcn_mfma_f32_16x16x32_bf16(a2f, b2f, acc2[n], 0, 0, 0);
        }
    }
    wsync();   // all W2 A-reads done before overwriting hbf with h2
#pragma unroll
    for (int n = 0; n < 8; ++n) {
#pragma unroll
        for (int r = 0; r < 4; ++r)
            hw_st(hw, r0 + r, n * 16 + cc, spf_(acc2[n][r] + b2v[n]));
    }
    wsync();

    // ---- V layer 3: o[16][16] = H2 @ W3pad  (4 MFMA, cols 8..15 zero) ----
    f32x4 acc3 = zf;
#pragma unroll
    for (int c = 0; c < 4; ++c) {
        const bf16x8 a3f = hw_ld(hw, cc, c * 32 + kq);
        const bf16x8 b3f = *(const bf16x8*)(w3b + cc * HVD + c * 32 + kq);
        acc3 = __builtin_amdgcn_mfma_f32_16x16x32_bf16(a3f, b3f, acc3, 0, 0, 0);
    }

    // ---- finalize V per row; rows 4q+r belong to THIS group's samples ----
    const float d0 = (cc < KVD) ? (vb3[cc] - h0g[cc]) : 0.f;
    float s_[4];
#pragma unroll
    for (int r = 0; r < 4; ++r) {
        const float e = (cc < KVD) ? (acc3[r] + d0) : 0.f;  // zero pad lanes
        s_[r] = e * e;
    }
#pragma unroll
    for (int m = 1; m < G; m <<= 1) {
#pragma unroll
        for (int r = 0; r < 4; ++r) s_[r] += __shfl_xor(s_[r], m);
    }
    const float Vx0 = s_[0] + EPS_C * p0;
    const float Vf0 = s_[1] + EPS_C * p1;
    const float Vx1 = s_[2] + EPS_C * p2;
    const float Vf1 = s_[3] + EPS_C * p3;

    const float t0 = BETA_C * Vx0;
    const float t1 = BETA_C * Vx1;
    const bool act0 = (Vf0 - t0) > 0.f;        // group-uniform
    const bool act1 = (Vf1 - t1) > 0.f;

    const bool lead = (gl == 0 && act0) || (gl == 1 && act1);
    unsigned long long bal = __ballot(lead);
    const int lane = threadIdx.x & 63, wv = threadIdx.x >> 6;
    const int rank = __popcll(bal & ((1ull << lane) - 1ull));
    if (lane == 0) wcnt[wv] = __popcll(bal);
    __syncthreads();
    if (threadIdx.x == 0) {
        int tot = 0;
        for (int i = 0; i < 4; ++i) { int c = wcnt[i]; wcnt[i] = tot; tot += c; }
        bbase = atomicAdd(cnt, tot);
    }
    __syncthreads();
    if (lead) {
        const int p = bbase + wcnt[wv] + rank;
        list[p] = (gl == 0) ? s0 : s1;
        tgt[p]  = (gl == 0) ? t0 : t1;
        vfb[p]  = (gl == 0) ? Vf0 : Vf1;       // V(fhatx) — solver's V(1)
    }
}

// ---- solver: persistent groups, PAIRED samples, SAFEGUARDED SECANT --------
// R9 LDS diet: w2L 32KB + packed-bf16 h1 8KB = 40960 B exactly -> 4 blocks/CU
// (16 waves/CU, 2x R8).  fxs removed (fx broadcast via __shfl), w3 reads from
// global (L1-resident).  launch_bounds 2nd arg stays 2 — the ONLY verified
// no-spill setting on this toolchain (arg2->128 VGPR ok; arg4->64 SPILL;
// arg5->48 SPILL).  Watch FETCH_SIZE: ~1.5MB = healthy, >10MB = spill.
__global__ __launch_bounds__(SBLK, 2) void k_solve(
    const float* __restrict__ vW1, const float* __restrict__ vb1,
    const unsigned short* __restrict__ w2s, const float* __restrict__ vb2,
    const unsigned short* __restrict__ w3s, const float* __restrict__ vb3,
    const float* __restrict__ h0g,
    float* __restrict__ out,
    const int* __restrict__ cnt, const int* __restrict__ list,
    const float* __restrict__ tgt, const float* __restrict__ vfb,
    int* __restrict__ qhead)
{
    __shared__ __align__(16) unsigned short w2L[HVD * HVD];  // 32 KB
    __shared__ unsigned h1s[SGPB][HVD];                      // 8 KB (2xbf16 packed)

    // ---- stage W2 to LDS (linear 16B copies; conflict-free reads) ----
    {
        const uint4* s2 = (const uint4*)w2s;
        uint4* d2 = (uint4*)w2L;
        for (int i = threadIdx.x; i < (HVD * HVD) / 8; i += SBLK) d2[i] = s2[i];
    }
    __syncthreads();   // only block-wide barrier; groups diverge after this

    const int gi = threadIdx.x >> 4;
    const int gl = threadIdx.x & (G - 1);
    const int n  = *cnt;
    unsigned* h1q = h1s[gi];
    const int lead = threadIdx.x & 48;   // group-lead LANE within the wave

    const int k0 = gl * 8;
    float b1v[8], b2v[8], d0c[8];
    {
        const float4 a = *(const float4*)(vb1 + k0);
        const float4 b = *(const float4*)(vb1 + k0 + 4);
        b1v[0]=a.x; b1v[1]=a.y; b1v[2]=a.z; b1v[3]=a.w;
        b1v[4]=b.x; b1v[5]=b.y; b1v[6]=b.z; b1v[7]=b.w;
        const float4 c = *(const float4*)(vb2 + k0);
        const float4 d = *(const float4*)(vb2 + k0 + 4);
        b2v[0]=c.x; b2v[1]=c.y; b2v[2]=c.z; b2v[3]=c.w;
        b2v[4]=d.x; b2v[5]=d.y; b2v[6]=d.z; b2v[7]=d.w;
#pragma unroll
        for (int cix = 0; cix < KVD; ++cix) d0c[cix] = vb3[cix] - h0g[cix];
    }

    int sA, sB; float tgA, tgB, fA0, fA1, fB0, fB1, n2A, n2B;
    float uA[8], uB[8];
    float gA, e1A, e2A, vA1, vA2, pgA, pvA;
    float gB, e1B, e2B, vB1, vB2, pgB, pvB;
    bool doneA, doneB;
    int itA, itB, obhA, obhB;

    auto grab = [&]() -> bool {
        int v = 0;
        if (gl == 0) v = atomicAdd(qhead, 2);
        v = __shfl(v, lead);
        if (v >= n) return false;
        const bool hasB = (v + 1) < n;
        sA = list[v]; tgA = tgt[v];
        const float vfA = vfb[v];
        float vfB;
        if (hasB) { sB = list[v + 1]; tgB = tgt[v + 1]; vfB = vfb[v + 1]; }
        else      { sB = sA;          tgB = tgA;        vfB = vfA; }
        fA0 = out[(size_t)sA * NN + gl];
        fA1 = out[(size_t)sA * NN + gl + 16];
        fB0 = out[(size_t)sB * NN + gl];
        fB1 = out[(size_t)sB * NN + gl + 16];
        // ||fx||^2 via group reduce (no LDS)
        float pa = fmaf(fA0, fA0, fA1 * fA1);
        float pb = fmaf(fB0, fB0, fB1 * fB1);
#pragma unroll
        for (int m = 1; m < G; m <<= 1) {
            pa += __shfl_xor(pa, m);
            pb += __shfl_xor(pb, m);
        }
        n2A = pa; n2B = pb;
        // u = fx @ vW1 cols k0..k0+7; fx broadcast via shfl (i unrolled ->
        // source operand is compile-time fA0/fA1)
#pragma unroll
        for (int j = 0; j < 8; ++j) { uA[j] = 0.f; uB[j] = 0.f; }
#pragma unroll
        for (int i = 0; i < NN; ++i) {
            const int src = lead + (i & 15);
            const float qx = __shfl((i < 16) ? fA0 : fA1, src);
            const float qy = __shfl((i < 16) ? fB0 : fB1, src);
            const float4 wa = *(const float4*)(vW1 + i * HVD + k0);
            const float4 wb = *(const float4*)(vW1 + i * HVD + k0 + 4);
            uA[0] = fmaf(qx, wa.x, uA[0]); uA[1] = fmaf(qx, wa.y, uA[1]);
            uA[2] = fmaf(qx, wa.z, uA[2]); uA[3] = fmaf(qx, wa.w, uA[3]);
            uA[4] = fmaf(qx, wb.x, uA[4]); uA[5] = fmaf(qx, wb.y, uA[5]);
            uA[6] = fmaf(qx, wb.z, uA[6]); uA[7] = fmaf(qx, wb.w, uA[7]);
            uB[0] = fmaf(qy, wa.x, uB[0]); uB[1] = fmaf(qy, wa.y, uB[1]);
            uB[2] = fmaf(qy, wa.z, uB[2]); uB[3] = fmaf(qy, wa.w, uB[3]);
            uB[4] = fmaf(qy, wb.x, uB[4]); uB[5] = fmaf(qy, wb.y, uB[5]);
            uB[6] = fmaf(qy, wb.z, uB[6]); uB[7] = fmaf(qy, wb.w, uB[7]);
        }
        // secant state: previous point = (1, vf) (known from k_setup)
        gA = sqrtf(tgA / vfA); e1A = 0.f; e2A = 1.f; vA1 = 0.f; vA2 = vfA;
        pgA = 1.f; pvA = vfA;
        gB = sqrtf(tgB / vfB); e1B = 0.f; e2B = 1.f; vB1 = 0.f; vB2 = vfB;
        pgB = 1.f; pvB = vfB;
        doneA = false; itA = 0; obhA = 0;
        doneB = !hasB; itB = 0; obhB = 0;
        return true;
    };
    if (!grab()) return;

    auto step = [&](bool& done, float& gamma, float& pg, float& pv,
                    float& e1, float& e2, float& v_e1, float& v_e2,
                    int& it, int& obh,
                    const float vp, const float target,
                    const int s, const float f0, const float f1) {
        if (done) return;
        // accept: at tolerance or bracket collapsed
        if (fabsf(vp - target) <= TOL_C || (e2 - e1) <= BRK_C) {
            out[(size_t)s * NN + gl]      = f0 * gamma;
            out[(size_t)s * NN + gl + 16] = f1 * gamma;
            done = true;
            return;
        }
        // ALWAYS contract the bracket with this eval.
        const float sa = sgn_(vp - target);
        const float s1 = sgn_(v_e1 - target);
        if (sa * s1 < 0.f) { e2 = gamma; v_e2 = vp; }
        else               { e1 = gamma; v_e1 = vp; }
        ++it;
        // secant proposal through (gamma, vp) and (pg, pv)
        const float newt = gamma - (vp - target) * (gamma - pg) / (vp - pv);
        pg = gamma; pv = vp;
        if (it < FORCE_C && newt >= e1 && newt <= e2) {   // NaN/inf fails -> below
            if (fabsf(newt - gamma) <= ACC_C) {
                // early accept: skip verification eval
                out[(size_t)s * NN + gl]      = f0 * newt;
                out[(size_t)s * NN + gl + 16] = f1 * newt;
                done = true;
                return;
            }
            gamma = newt;
        } else if (newt > e2 && e2 >= 1.0f) {
            // no-root band signature: root claimed above never-contracted e2=1
            if (++obh >= 2) {
                out[(size_t)s * NN + gl]      = f0;       // gamma = 1 exactly
                out[(size_t)s * NN + gl + 16] = f1;
                done = true;
                return;
            }
            gamma = 0.5f * (e1 + e2);                     // one confirming probe
        } else {
            gamma = 0.5f * (e1 + e2);                     // guaranteed shrink
        }
        if (it >= MAXIT_C) {
            out[(size_t)s * NN + gl]      = f0 * gamma;
            out[(size_t)s * NN + gl + 16] = f1 * gamma;
            done = true;
        }
    };

    for (;;) {
        float vpA, vpB;
        veval2_sec(gl, uA, uB, gA, gB, h1q, n2A, n2B,
                   b1v, b2v, d0c, w2L, w3s, vpA, vpB);
        step(doneA, gA, pgA, pvA, e1A, e2A, vA1, vA2, itA, obhA, vpA, tgA, sA, fA0, fA1);
        step(doneB, gB, pgB, pvB, e1B, e2B, vB1, vB2, itB, obhB, vpB, tgB, sB, fB0, fB1);
        if (doneA && doneB) {
            if (!grab()) break;
        }
    }
}

extern "C" void kernel_launch(void* const* d_in, const int* in_sizes, int n_in,
                              void* d_out, int out_size, void* d_ws, size_t ws_size,
                              hipStream_t stream)
{
    const float* x   = (const float*)d_in[0];
    const float* fW1 = (const float*)d_in[1];
    const float* fb1 = (const float*)d_in[2];
    const float* fW2 = (const float*)d_in[3];
    const float* fb2 = (const float*)d_in[4];
    const float* fW3 = (const float*)d_in[5];
    const float* fb3 = (const float*)d_in[6];
    const float* vW1 = (const float*)d_in[7];
    const float* vb1 = (const float*)d_in[8];
    const float* vW2 = (const float*)d_in[9];
    const float* vb2 = (const float*)d_in[10];
    const float* vW3 = (const float*)d_in[11];
    const float* vb3 = (const float*)d_in[12];
    float* out = (float*)d_out;

    char* ws = (char*)d_ws;
    int*   cnt   = (int*)ws;                                 // 4 B
    int*   qhead = (int*)(ws + 4);                           // 4 B
    float* h0g   = (float*)(ws + 64);                        // 8 floats
    int*   list  = (int*)(ws + 128);                         // BN ints
    float* tgt   = (float*)(ws + 128 + (size_t)BN * 4);      // BN floats
    float* vfb   = (float*)(ws + 128 + (size_t)BN * 8);      // BN floats
    unsigned short* w1b = (unsigned short*)(ws + 128 + (size_t)BN * 12);  // 8 KB (16B-aligned)
    unsigned short* w2b = w1b + HVD * NN;                    // 32 KB
    unsigned short* w3b = w2b + HVD * HVD;                   // 4 KB
    unsigned short* w2s = w3b + 16 * HVD;                    // 32 KB (solver, [k][col])
    unsigned short* w3s = w2s + HVD * HVD;                   // 2 KB  (solver, [k][c])

    hipMemsetAsync(ws, 0, 8, stream);                        // cnt + qhead

    hipLaunchKernelGGL(k_h0, dim3(1), dim3(HVD), 0, stream,
                       vb1, vW2, vb2, vW3, vb3, h0g);

    hipLaunchKernelGGL(k_wprep, dim3(32), dim3(256), 0, stream,
                       vW1, vW2, vW3, w1b, w2b, w3b, w2s, w3s);

    hipLaunchKernelGGL(k_setup, dim3(BN / (GPB * 2)), dim3(256), 0, stream,
                       x, fW1, fb1, fW2, fb2, fW3, fb3,
                       vb1, vb2, vb3, w1b, w2b, w3b,
                       h0g, out, cnt, list, tgt, vfb);

    hipLaunchKernelGGL(k_solve, dim3(NQBLK), dim3(SBLK), 0, stream,
                       vW1, vb1, w2s, vb2, w3s, vb3,
                       h0g, out, cnt, list, tgt, vfb, qhead);
}

// Round 10
// 303.793 us; speedup vs baseline: 1.4629x; 1.4629x over previous
//
#include <hip/hip_runtime.h>
#include <math.h>

#define BETA_C   0.99f
#define TOL_C    1e-4f
#define ACC_C    1e-3f   // early-accept: secant step smaller than this -> done
#define BRK_C    1e-3f   // bracket-width accept (same accuracy class as ACC_C)
#define FORCE_C  6       // secant gets 6 tries, then pure bisection
#define MAXIT_C  1000
#define EPS_C    1e-3f
#define BN       65536
#define NN       32
#define HFD      25
#define HVD      128
#define KVD      8
#define G        16   // lanes per cooperative group
#define GPB      16   // groups per 256-thread block (k_setup; 2 samples/group)
#define SGPB     16   // groups per 256-thread solver block
#define SBLK     256  // solver block threads
#define NQBLK    768  // solver blocks (3 resident/CU at 48KB LDS = all resident)

typedef __attribute__((ext_vector_type(8))) short bf16x8;  // 8 bf16 (4 VGPRs)
typedef __attribute__((ext_vector_type(8))) unsigned short u16x8;
typedef __attribute__((ext_vector_type(4))) float f32x4;   // 4 fp32 acc

// wave-internal LDS ordering (groups live inside one wave; no block barrier
// inside the divergent solve loop).
__device__ __forceinline__ void wsync() {
    __builtin_amdgcn_wave_barrier();
    __threadfence_block();
    __builtin_amdgcn_wave_barrier();
}

__device__ __forceinline__ float sp_(float x) {
    return fmaxf(x, 0.f) + log1pf(expf(-fabsf(x)));
}
// fast softplus: __expf/__logf (rel err ~1e-6; negligible vs TOL / bf16 budget)
__device__ __forceinline__ float spf_(float x) {
    return fmaxf(x, 0.f) + __logf(1.f + __expf(-fabsf(x)));
}
__device__ __forceinline__ float sgn_(float d) {
    return (d > 0.f) ? 1.f : ((d < 0.f) ? -1.f : 0.f);
}
__device__ __forceinline__ unsigned short f2bf(float f) {   // RNE f32->bf16
    unsigned int u = __float_as_uint(f);
    u += 0x7FFFu + ((u >> 16) & 1u);
    return (unsigned short)(u >> 16);
}
__device__ __forceinline__ float bf2f(unsigned short u) {
    return __uint_as_float(((unsigned int)u) << 16);
}

// ---- swizzled per-wave LDS activation tiles (G4: XOR row bits into bank bits)
__device__ __forceinline__ void aw_st(unsigned short* aw, int row, int col, float v) {
    const int b = (row * 64 + col * 2) ^ ((row & 3) << 4);
    *(unsigned short*)((char*)aw + b) = f2bf(v);
}
__device__ __forceinline__ bf16x8 aw_ld(const unsigned short* aw, int row, int k) {
    const int b = (row * 64 + k * 2) ^ ((row & 3) << 4);
    return *(const bf16x8*)((const char*)aw + b);
}
__device__ __forceinline__ void hw_st(unsigned short* hw, int row, int col, float v) {
    const int b = (row * 256 + col * 2) ^ ((row & 7) << 4);
    *(unsigned short*)((char*)hw + b) = f2bf(v);
}
__device__ __forceinline__ bf16x8 hw_ld(const unsigned short* hw, int row, int k) {
    const int b = (row * 256 + k * 2) ^ ((row & 7) << 4);
    return *(const bf16x8*)((const char*)hw + b);
}

// ---------------------------------------------------------------------------
// paired V-ONLY eval (k_solve, secant solver): V(fxA*gA), V(fxB*gB), sharing
// all W2 loads from LDS.  R10: h1 back to FP32 (R9's bf16-quantized h1 made
// V(gamma) a step function with jumps >> TOL=1e-4 -> the TOL accept never
// fired and every sample ground to the BRK_C bisection floor: eval count
// ~2x, k_solve 118->275us).  Swizzled float2 layout: store (j<<4)|gl is
// bank-conflict-FREE (banks gl*2); read ((k&7)<<4)|(k>>3) is group-uniform
// -> broadcast.  w3 reads from global (2KB, L1-resident).
__device__ __forceinline__ void veval2_sec(
    const int gl, const float (&uA)[8], const float (&uB)[8],
    const float gA, const float gB,
    float2* h1q, const float n2A, const float n2B,
    const float (&b1v)[8], const float (&b2v)[8], const float (&d0c)[8],
    const unsigned short* w2L, const unsigned short* __restrict__ w3s,
    float& VA, float& VB)
{
    const int k0 = gl * 8;
#pragma unroll
    for (int j = 0; j < 8; ++j) {
        const float preA = fmaf(gA, uA[j], b1v[j]);
        const float preB = fmaf(gB, uB[j], b1v[j]);
        h1q[(j << 4) | gl] = make_float2(spf_(preA), spf_(preB));  // k = gl*8+j
    }
    wsync();
    float aA[8], aB[8];
#pragma unroll
    for (int j = 0; j < 8; ++j) { aA[j] = 0.f; aB[j] = 0.f; }
#pragma unroll 4
    for (int k = 0; k < HVD; ++k) {
        const float2 q = h1q[((k & 7) << 4) | (k >> 3)];   // uniform -> broadcast
        const u16x8 wv = *(const u16x8*)(w2L + k * HVD + k0);  // ds_read_b128
#pragma unroll
        for (int j = 0; j < 8; ++j) {
            const float w = bf2f(wv[j]);
            aA[j] = fmaf(q.x, w, aA[j]);
            aB[j] = fmaf(q.y, w, aB[j]);
        }
    }
    wsync();
    float oA[KVD], oB[KVD];
#pragma unroll
    for (int c = 0; c < KVD; ++c) { oA[c] = 0.f; oB[c] = 0.f; }
#pragma unroll
    for (int j = 0; j < 8; ++j) {
        const float h2A = spf_(aA[j] + b2v[j]);
        const float h2B = spf_(aB[j] + b2v[j]);
        const u16x8 w3v = *(const u16x8*)(w3s + (k0 + j) * KVD);   // global, L1
#pragma unroll
        for (int c = 0; c < 8; ++c) {
            const float w3 = bf2f(w3v[c]);
            oA[c] = fmaf(h2A, w3, oA[c]);
            oB[c] = fmaf(h2B, w3, oB[c]);
        }
    }
#pragma unroll
    for (int m = 1; m < G; m <<= 1) {
#pragma unroll
        for (int c = 0; c < KVD; ++c) {
            oA[c] += __shfl_xor(oA[c], m);
            oB[c] += __shfl_xor(oB[c], m);
        }
    }
    float vvA = 0.f, vvB = 0.f;
#pragma unroll
    for (int c = 0; c < KVD; ++c) {
        const float eA = oA[c] + d0c[c];
        const float eB = oB[c] + d0c[c];
        vvA = fmaf(eA, eA, vvA);
        vvB = fmaf(eB, eB, vvB);
    }
    VA = vvA + EPS_C * gA * gA * n2A;
    VB = vvB + EPS_C * gB * gB * n2B;
}

// ---- h0 = V-MLP(0) : weight-only, one tiny block --------------------------
__global__ __launch_bounds__(128) void k_h0(
    const float* __restrict__ vb1, const float* __restrict__ vW2,
    const float* __restrict__ vb2, const float* __restrict__ vW3,
    const float* __restrict__ vb3, float* __restrict__ h0g)
{
    __shared__ float h1s[HVD];
    __shared__ float h2s[HVD];
    int j = threadIdx.x;
    h1s[j] = sp_(vb1[j]);
    __syncthreads();
    float a = vb2[j];
    for (int k = 0; k < HVD; ++k) a = fmaf(h1s[k], vW2[k * HVD + j], a);
    h2s[j] = sp_(a);
    __syncthreads();
    if (j < KVD) {
        float acc = vb3[j];
        for (int k = 0; k < HVD; ++k) acc = fmaf(h2s[k], vW3[k * KVD + j], acc);
        h0g[j] = acc;
    }
}

// ---- weight prep: V-net weights -> bf16 ------------------------------------
__global__ __launch_bounds__(256) void k_wprep(
    const float* __restrict__ vW1, const float* __restrict__ vW2,
    const float* __restrict__ vW3,
    unsigned short* __restrict__ w1b, unsigned short* __restrict__ w2b,
    unsigned short* __restrict__ w3b,
    unsigned short* __restrict__ w2s, unsigned short* __restrict__ w3s)
{
    const int t = blockIdx.x * 256 + threadIdx.x;
    const int nth = gridDim.x * 256;
    for (int i = t; i < HVD * NN; i += nth) {          // [128 col][32 k]
        const int col = i >> 5, k = i & 31;
        w1b[i] = f2bf(vW1[k * HVD + col]);
    }
    for (int i = t; i < HVD * HVD; i += nth) {         // [128 col][128 k]
        const int col = i >> 7, k = i & 127;
        w2b[i] = f2bf(vW2[k * HVD + col]);
    }
    for (int i = t; i < 16 * HVD; i += nth) {          // [16 col][128 k], cols 8..15 = 0
        const int c = i >> 7, k = i & 127;
        w3b[i] = (c < KVD) ? f2bf(vW3[k * KVD + c]) : (unsigned short)0;
    }
    for (int i = t; i < HVD * HVD; i += nth)           // [k][col] elementwise
        w2s[i] = f2bf(vW2[i]);
    for (int i = t; i < HVD * KVD; i += nth)           // [k][c] elementwise
        w3s[i] = f2bf(vW3[i]);
}

// ---- setup: f-net fp32 (spf_ softplus), V-net via bf16 MFMA ---------------
// f-net processes BOTH samples in one pass (2-way ILP on the dependent fma
// chains + shared fW loads; per-sample accumulation order unchanged).
__global__ __launch_bounds__(256, 4) void k_setup(
    const float* __restrict__ x_g,
    const float* __restrict__ fW1, const float* __restrict__ fb1,
    const float* __restrict__ fW2, const float* __restrict__ fb2,
    const float* __restrict__ fW3, const float* __restrict__ fb3,
    const float* __restrict__ vb1, const float* __restrict__ vb2,
    const float* __restrict__ vb3,
    const unsigned short* __restrict__ w1b,
    const unsigned short* __restrict__ w2b,
    const unsigned short* __restrict__ w3b,
    const float* __restrict__ h0g,
    float* __restrict__ out,
    int* __restrict__ cnt, int* __restrict__ list, float* __restrict__ tgt,
    float* __restrict__ vfb)
{
    __shared__ float2 xs[GPB][NN + 1];                       // 4.2 KB (f-net x)
    __shared__ float2 fh1[GPB][HFD + 1];                     // 3.3 KB (A,B pair)
    __shared__ float2 fh2[GPB][HFD + 1];                     // 3.3 KB
    __shared__ __align__(16) unsigned short abf[4][16 * 32]; // 4 KB  (Z rows bf16)
    __shared__ __align__(16) unsigned short hbf[4][16 * HVD];// 16 KB (h1/h2 reuse)
    __shared__ int wcnt[4];
    __shared__ int bbase;

    const int tid = threadIdx.x;
    const int gi = tid >> 4;          // group 0..15
    const int gl = tid & (G - 1);
    const int w  = tid >> 6;          // wave 0..3
    const int l  = tid & 63;
    const int q  = l >> 4;            // lane quad within wave (== gi & 3)
    const int cc = l & 15;
    const int sb = (blockIdx.x * GPB + gi) * 2;
    const int s0 = sb, s1 = sb + 1;
    unsigned short* aw = abf[w];
    unsigned short* hw = hbf[w];

    // ---- stage x (fp32 for f-net, bf16 rows for V A-operand) ----
    const float xa0 = x_g[(size_t)s0 * NN + gl];
    const float xa1 = x_g[(size_t)s0 * NN + gl + 16];
    const float xb0 = x_g[(size_t)s1 * NN + gl];
    const float xb1 = x_g[(size_t)s1 * NN + gl + 16];
    xs[gi][gl]      = make_float2(xa0, xb0);
    xs[gi][gl + 16] = make_float2(xa1, xb1);
    const int r0 = 4 * q;             // this group's base row in the wave tile
    aw_st(aw, r0,     gl,      xa0); aw_st(aw, r0,     gl + 16, xa1);
    aw_st(aw, r0 + 2, gl,      xb0); aw_st(aw, r0 + 2, gl + 16, xb1);
    wsync();

    // ---- f-net, both samples interleaved (fp32 fma, fast softplus) ----
    float fA0, fA1, fB0, fB1;
    for (int uu = gl; uu < HFD; uu += G) {
        float a0 = fb1[uu];
        float a1 = a0;
#pragma unroll
        for (int i = 0; i < NN; ++i) {
            const float2 xv2 = xs[gi][i];
            const float wv = fW1[i * HFD + uu];
            a0 = fmaf(xv2.x, wv, a0);
            a1 = fmaf(xv2.y, wv, a1);
        }
        fh1[gi][uu] = make_float2(spf_(a0), spf_(a1));
    }
    wsync();
    for (int uu = gl; uu < HFD; uu += G) {
        float a0 = fb2[uu];
        float a1 = a0;
#pragma unroll
        for (int i = 0; i < HFD; ++i) {
            const float2 h = fh1[gi][i];
            const float wv = fW2[i * HFD + uu];
            a0 = fmaf(h.x, wv, a0);
            a1 = fmaf(h.y, wv, a1);
        }
        fh2[gi][uu] = make_float2(spf_(a0), spf_(a1));
    }
    wsync();
    {
        float A0 = fb3[gl], A1 = fb3[gl + 16];
        float B0 = A0,      B1 = A1;
#pragma unroll
        for (int i = 0; i < HFD; ++i) {
            const float2 h = fh2[gi][i];
            const float wa = fW3[i * NN + gl];
            const float wb = fW3[i * NN + gl + 16];
            A0 = fmaf(h.x, wa, A0); A1 = fmaf(h.x, wb, A1);
            B0 = fmaf(h.y, wa, B0); B1 = fmaf(h.y, wb, B1);
        }
        out[(size_t)s0 * NN + gl]      = A0;
        out[(size_t)s0 * NN + gl + 16] = A1;
        out[(size_t)s1 * NN + gl]      = B0;
        out[(size_t)s1 * NN + gl + 16] = B1;
        aw_st(aw, r0 + 1, gl, A0); aw_st(aw, r0 + 1, gl + 16, A1);
        aw_st(aw, r0 + 3, gl, B0); aw_st(aw, r0 + 3, gl + 16, B1);
        fA0 = A0; fA1 = A1; fB0 = B0; fB1 = B1;
    }
    wsync();

    // ---- ||z||^2 per row (fp32 exact) ----
    float p0 = fmaf(xa0, xa0, xa1 * xa1);
    float p1 = fmaf(fA0, fA0, fA1 * fA1);
    float p2 = fmaf(xb0, xb0, xb1 * xb1);
    float p3 = fmaf(fB0, fB0, fB1 * fB1);
#pragma unroll
    for (int m = 1; m < G; m <<= 1) {
        p0 += __shfl_xor(p0, m); p1 += __shfl_xor(p1, m);
        p2 += __shfl_xor(p2, m); p3 += __shfl_xor(p3, m);
    }

    float b1v[8], b2v[8];
#pragma unroll
    for (int n = 0; n < 8; ++n) {
        b1v[n] = vb1[n * 16 + cc];    // col = n*16 + cc
        b2v[n] = vb2[n * 16 + cc];
    }

    const int kq = (l >> 4) * 8;      // this lane's k-offset within a K=32 chunk
    const f32x4 zf = {0.f, 0.f, 0.f, 0.f};

    // ---- V layer 1: u[16][128] = Z[16][32] @ W1  (8 MFMA, K=32 exact) ----
    const bf16x8 afr = aw_ld(aw, cc, kq);        // A: row=l&15, k=8*(l>>4)+j
    f32x4 acc1[8];
#pragma unroll
    for (int n = 0; n < 8; ++n) {
        const bf16x8 bfr = *(const bf16x8*)(w1b + (n * 16 + cc) * 32 + kq);
        acc1[n] = __builtin_amdgcn_mfma_f32_16x16x32_bf16(afr, bfr, zf, 0, 0, 0);
    }
    // h1 = softplus(u + b1) -> hbf (C layout: row=4q+r, col=n*16+cc)
#pragma unroll
    for (int n = 0; n < 8; ++n) {
#pragma unroll
        for (int r = 0; r < 4; ++r)
            hw_st(hw, r0 + r, n * 16 + cc, spf_(acc1[n][r] + b1v[n]));
    }
    wsync();

    // ---- V layer 2: a2[16][128] = H1 @ W2  (32 MFMA) ----
    f32x4 acc2[8];
#pragma unroll
    for (int n = 0; n < 8; ++n) acc2[n] = zf;
#pragma unroll
    for (int c = 0; c < 4; ++c) {
        const bf16x8 a2f = hw_ld(hw, cc, c * 32 + kq);
#pragma unroll
        for (int n = 0; n < 8; ++n) {
            const bf16x8 b2f = *(const bf16x8*)(w2b + (n * 16 + cc) * HVD + c * 32 + kq);
            acc2[n] = __builtin_amdgcn_mfma_f32_16x16x32_bf16(a2f, b2f, acc2[n], 0, 0, 0);
        }
    }
    wsync();   // all W2 A-reads done before overwriting hbf with h2
#pragma unroll
    for (int n = 0; n < 8; ++n) {
#pragma unroll
        for (int r = 0; r < 4; ++r)
            hw_st(hw, r0 + r, n * 16 + cc, spf_(acc2[n][r] + b2v[n]));
    }
    wsync();

    // ---- V layer 3: o[16][16] = H2 @ W3pad  (4 MFMA, cols 8..15 zero) ----
    f32x4 acc3 = zf;
#pragma unroll
    for (int c = 0; c < 4; ++c) {
        const bf16x8 a3f = hw_ld(hw, cc, c * 32 + kq);
        const bf16x8 b3f = *(const bf16x8*)(w3b + cc * HVD + c * 32 + kq);
        acc3 = __builtin_amdgcn_mfma_f32_16x16x32_bf16(a3f, b3f, acc3, 0, 0, 0);
    }

    // ---- finalize V per row; rows 4q+r belong to THIS group's samples ----
    const float d0 = (cc < KVD) ? (vb3[cc] - h0g[cc]) : 0.f;
    float s_[4];
#pragma unroll
    for (int r = 0; r < 4; ++r) {
        const float e = (cc < KVD) ? (acc3[r] + d0) : 0.f;  // zero pad lanes
        s_[r] = e * e;
    }
#pragma unroll
    for (int m = 1; m < G; m <<= 1) {
#pragma unroll
        for (int r = 0; r < 4; ++r) s_[r] += __shfl_xor(s_[r], m);
    }
    const float Vx0 = s_[0] + EPS_C * p0;
    const float Vf0 = s_[1] + EPS_C * p1;
    const float Vx1 = s_[2] + EPS_C * p2;
    const float Vf1 = s_[3] + EPS_C * p3;

    const float t0 = BETA_C * Vx0;
    const float t1 = BETA_C * Vx1;
    const bool act0 = (Vf0 - t0) > 0.f;        // group-uniform
    const bool act1 = (Vf1 - t1) > 0.f;

    const bool lead = (gl == 0 && act0) || (gl == 1 && act1);
    unsigned long long bal = __ballot(lead);
    const int lane = threadIdx.x & 63, wv = threadIdx.x >> 6;
    const int rank = __popcll(bal & ((1ull << lane) - 1ull));
    if (lane == 0) wcnt[wv] = __popcll(bal);
    __syncthreads();
    if (threadIdx.x == 0) {
        int tot = 0;
        for (int i = 0; i < 4; ++i) { int c = wcnt[i]; wcnt[i] = tot; tot += c; }
        bbase = atomicAdd(cnt, tot);
    }
    __syncthreads();
    if (lead) {
        const int p = bbase + wcnt[wv] + rank;
        list[p] = (gl == 0) ? s0 : s1;
        tgt[p]  = (gl == 0) ? t0 : t1;
        vfb[p]  = (gl == 0) ? Vf0 : Vf1;       // V(fhatx) — solver's V(1)
    }
}

// ---- solver: persistent groups, PAIRED samples, SAFEGUARDED SECANT --------
// R10: fp32 h1 restored (swizzled float2: conflict-free store, broadcast
// read); LDS = 32K w2L + 16K h1 = 48KB -> 3 blocks/CU (12 waves, 1.5x R8).
// launch_bounds 2nd arg stays 2 — the ONLY verified no-spill setting
// (arg2->128 VGPR ok; arg4->64 SPILL; arg5->48 SPILL).  FETCH ~1.5MB =
// healthy; >10MB = spill tripwire.
__global__ __launch_bounds__(SBLK, 2) void k_solve(
    const float* __restrict__ vW1, const float* __restrict__ vb1,
    const unsigned short* __restrict__ w2s, const float* __restrict__ vb2,
    const unsigned short* __restrict__ w3s, const float* __restrict__ vb3,
    const float* __restrict__ h0g,
    float* __restrict__ out,
    const int* __restrict__ cnt, const int* __restrict__ list,
    const float* __restrict__ tgt, const float* __restrict__ vfb,
    int* __restrict__ qhead)
{
    __shared__ __align__(16) unsigned short w2L[HVD * HVD];  // 32 KB
    __shared__ __align__(8) float2 h1s[SGPB][HVD];           // 16 KB (fp32 pair)

    // ---- stage W2 to LDS (linear 16B copies; conflict-free reads) ----
    {
        const uint4* s2 = (const uint4*)w2s;
        uint4* d2 = (uint4*)w2L;
        for (int i = threadIdx.x; i < (HVD * HVD) / 8; i += SBLK) d2[i] = s2[i];
    }
    __syncthreads();   // only block-wide barrier; groups diverge after this

    const int gi = threadIdx.x >> 4;
    const int gl = threadIdx.x & (G - 1);
    const int n  = *cnt;
    float2* h1q = h1s[gi];
    const int lead = threadIdx.x & 48;   // group-lead LANE within the wave

    const int k0 = gl * 8;
    float b1v[8], b2v[8], d0c[8];
    {
        const float4 a = *(const float4*)(vb1 + k0);
        const float4 b = *(const float4*)(vb1 + k0 + 4);
        b1v[0]=a.x; b1v[1]=a.y; b1v[2]=a.z; b1v[3]=a.w;
        b1v[4]=b.x; b1v[5]=b.y; b1v[6]=b.z; b1v[7]=b.w;
        const float4 c = *(const float4*)(vb2 + k0);
        const float4 d = *(const float4*)(vb2 + k0 + 4);
        b2v[0]=c.x; b2v[1]=c.y; b2v[2]=c.z; b2v[3]=c.w;
        b2v[4]=d.x; b2v[5]=d.y; b2v[6]=d.z; b2v[7]=d.w;
#pragma unroll
        for (int cix = 0; cix < KVD; ++cix) d0c[cix] = vb3[cix] - h0g[cix];
    }

    int sA, sB; float tgA, tgB, fA0, fA1, fB0, fB1, n2A, n2B;
    float uA[8], uB[8];
    float gA, e1A, e2A, vA1, vA2, pgA, pvA;
    float gB, e1B, e2B, vB1, vB2, pgB, pvB;
    bool doneA, doneB;
    int itA, itB, obhA, obhB;

    auto grab = [&]() -> bool {
        int v = 0;
        if (gl == 0) v = atomicAdd(qhead, 2);
        v = __shfl(v, lead);
        if (v >= n) return false;
        const bool hasB = (v + 1) < n;
        sA = list[v]; tgA = tgt[v];
        const float vfA = vfb[v];
        float vfB;
        if (hasB) { sB = list[v + 1]; tgB = tgt[v + 1]; vfB = vfb[v + 1]; }
        else      { sB = sA;          tgB = tgA;        vfB = vfA; }
        fA0 = out[(size_t)sA * NN + gl];
        fA1 = out[(size_t)sA * NN + gl + 16];
        fB0 = out[(size_t)sB * NN + gl];
        fB1 = out[(size_t)sB * NN + gl + 16];
        // ||fx||^2 via group reduce (no LDS)
        float pa = fmaf(fA0, fA0, fA1 * fA1);
        float pb = fmaf(fB0, fB0, fB1 * fB1);
#pragma unroll
        for (int m = 1; m < G; m <<= 1) {
            pa += __shfl_xor(pa, m);
            pb += __shfl_xor(pb, m);
        }
        n2A = pa; n2B = pb;
        // u = fx @ vW1 cols k0..k0+7; fx broadcast via shfl (i unrolled ->
        // source operand is compile-time fA0/fA1)
#pragma unroll
        for (int j = 0; j < 8; ++j) { uA[j] = 0.f; uB[j] = 0.f; }
#pragma unroll
        for (int i = 0; i < NN; ++i) {
            const int src = lead + (i & 15);
            const float qx = __shfl((i < 16) ? fA0 : fA1, src);
            const float qy = __shfl((i < 16) ? fB0 : fB1, src);
            const float4 wa = *(const float4*)(vW1 + i * HVD + k0);
            const float4 wb = *(const float4*)(vW1 + i * HVD + k0 + 4);
            uA[0] = fmaf(qx, wa.x, uA[0]); uA[1] = fmaf(qx, wa.y, uA[1]);
            uA[2] = fmaf(qx, wa.z, uA[2]); uA[3] = fmaf(qx, wa.w, uA[3]);
            uA[4] = fmaf(qx, wb.x, uA[4]); uA[5] = fmaf(qx, wb.y, uA[5]);
            uA[6] = fmaf(qx, wb.z, uA[6]); uA[7] = fmaf(qx, wb.w, uA[7]);
            uB[0] = fmaf(qy, wa.x, uB[0]); uB[1] = fmaf(qy, wa.y, uB[1]);
            uB[2] = fmaf(qy, wa.z, uB[2]); uB[3] = fmaf(qy, wa.w, uB[3]);
            uB[4] = fmaf(qy, wb.x, uB[4]); uB[5] = fmaf(qy, wb.y, uB[5]);
            uB[6] = fmaf(qy, wb.z, uB[6]); uB[7] = fmaf(qy, wb.w, uB[7]);
        }
        // secant state: previous point = (1, vf) (known from k_setup)
        gA = sqrtf(tgA / vfA); e1A = 0.f; e2A = 1.f; vA1 = 0.f; vA2 = vfA;
        pgA = 1.f; pvA = vfA;
        gB = sqrtf(tgB / vfB); e1B = 0.f; e2B = 1.f; vB1 = 0.f; vB2 = vfB;
        pgB = 1.f; pvB = vfB;
        doneA = false; itA = 0; obhA = 0;
        doneB = !hasB; itB = 0; obhB = 0;
        return true;
    };
    if (!grab()) return;

    auto step = [&](bool& done, float& gamma, float& pg, float& pv,
                    float& e1, float& e2, float& v_e1, float& v_e2,
                    int& it, int& obh,
                    const float vp, const float target,
                    const int s, const float f0, const float f1) {
        if (done) return;
        // accept: at tolerance or bracket collapsed
        if (fabsf(vp - target) <= TOL_C || (e2 - e1) <= BRK_C) {
            out[(size_t)s * NN + gl]      = f0 * gamma;
            out[(size_t)s * NN + gl + 16] = f1 * gamma;
            done = true;
            return;
        }
        // ALWAYS contract the bracket with this eval.
        const float sa = sgn_(vp - target);
        const float s1 = sgn_(v_e1 - target);
        if (sa * s1 < 0.f) { e2 = gamma; v_e2 = vp; }
        else               { e1 = gamma; v_e1 = vp; }
        ++it;
        // secant proposal through (gamma, vp) and (pg, pv)
        const float newt = gamma - (vp - target) * (gamma - pg) / (vp - pv);
        pg = gamma; pv = vp;
        if (it < FORCE_C && newt >= e1 && newt <= e2) {   // NaN/inf fails -> below
            if (fabsf(newt - gamma) <= ACC_C) {
                // early accept: skip verification eval
                out[(size_t)s * NN + gl]      = f0 * newt;
                out[(size_t)s * NN + gl + 16] = f1 * newt;
                done = true;
                return;
            }
            gamma = newt;
        } else if (newt > e2 && e2 >= 1.0f) {
            // no-root band signature: root claimed above never-contracted e2=1
            if (++obh >= 2) {
                out[(size_t)s * NN + gl]      = f0;       // gamma = 1 exactly
                out[(size_t)s * NN + gl + 16] = f1;
                done = true;
                return;
            }
            gamma = 0.5f * (e1 + e2);                     // one confirming probe
        } else {
            gamma = 0.5f * (e1 + e2);                     // guaranteed shrink
        }
        if (it >= MAXIT_C) {
            out[(size_t)s * NN + gl]      = f0 * gamma;
            out[(size_t)s * NN + gl + 16] = f1 * gamma;
            done = true;
        }
    };

    for (;;) {
        float vpA, vpB;
        veval2_sec(gl, uA, uB, gA, gB, h1q, n2A, n2B,
                   b1v, b2v, d0c, w2L, w3s, vpA, vpB);
        step(doneA, gA, pgA, pvA, e1A, e2A, vA1, vA2, itA, obhA, vpA, tgA, sA, fA0, fA1);
        step(doneB, gB, pgB, pvB, e1B, e2B, vB1, vB2, itB, obhB, vpB, tgB, sB, fB0, fB1);
        if (doneA && doneB) {
            if (!grab()) break;
        }
    }
}

extern "C" void kernel_launch(void* const* d_in, const int* in_sizes, int n_in,
                              void* d_out, int out_size, void* d_ws, size_t ws_size,
                              hipStream_t stream)
{
    const float* x   = (const float*)d_in[0];
    const float* fW1 = (const float*)d_in[1];
    const float* fb1 = (const float*)d_in[2];
    const float* fW2 = (const float*)d_in[3];
    const float* fb2 = (const float*)d_in[4];
    const float* fW3 = (const float*)d_in[5];
    const float* fb3 = (const float*)d_in[6];
    const float* vW1 = (const float*)d_in[7];
    const float* vb1 = (const float*)d_in[8];
    const float* vW2 = (const float*)d_in[9];
    const float* vb2 = (const float*)d_in[10];
    const float* vW3 = (const float*)d_in[11];
    const float* vb3 = (const float*)d_in[12];
    float* out = (float*)d_out;

    char* ws = (char*)d_ws;
    int*   cnt   = (int*)ws;                                 // 4 B
    int*   qhead = (int*)(ws + 4);                           // 4 B
    float* h0g   = (float*)(ws + 64);                        // 8 floats
    int*   list  = (int*)(ws + 128);                         // BN ints
    float* tgt   = (float*)(ws + 128 + (size_t)BN * 4);      // BN floats
    float* vfb   = (float*)(ws + 128 + (size_t)BN * 8);      // BN floats
    unsigned short* w1b = (unsigned short*)(ws + 128 + (size_t)BN * 12);  // 8 KB (16B-aligned)
    unsigned short* w2b = w1b + HVD * NN;                    // 32 KB
    unsigned short* w3b = w2b + HVD * HVD;                   // 4 KB
    unsigned short* w2s = w3b + 16 * HVD;                    // 32 KB (solver, [k][col])
    unsigned short* w3s = w2s + HVD * HVD;                   // 2 KB  (solver, [k][c])

    hipMemsetAsync(ws, 0, 8, stream);                        // cnt + qhead

    hipLaunchKernelGGL(k_h0, dim3(1), dim3(HVD), 0, stream,
                       vb1, vW2, vb2, vW3, vb3, h0g);

    hipLaunchKernelGGL(k_wprep, dim3(32), dim3(256), 0, stream,
                       vW1, vW2, vW3, w1b, w2b, w3b, w2s, w3s);

    hipLaunchKernelGGL(k_setup, dim3(BN / (GPB * 2)), dim3(256), 0, stream,
                       x, fW1, fb1, fW2, fb2, fW3, fb3,
                       vb1, vb2, vb3, w1b, w2b, w3b,
                       h0g, out, cnt, list, tgt, vfb);

    hipLaunchKernelGGL(k_solve, dim3(NQBLK), dim3(SBLK), 0, stream,
                       vW1, vb1, w2s, vb2, w3s, vb3,
                       h0g, out, cnt, list, tgt, vfb, qhead);
}

// Round 11
// 289.980 us; speedup vs baseline: 1.5325x; 1.0476x over previous
//
#include <hip/hip_runtime.h>
#include <math.h>

#define BETA_C   0.99f
#define TOL_C    1e-4f
#define ACC_C    2e-3f   // early-accept: secant step smaller than this -> done
#define BRK_C    2e-3f   // bracket-width accept (out err ~2e-3*|fx|, budget 0.069)
#define FORCE_C  6       // secant gets 6 tries, then falsi/bisection alternation
#define MAXIT_C  1000
#define EPS_C    1e-3f
#define BN       65536
#define NN       32
#define HFD      25
#define HVD      128
#define KVD      8
#define G        16   // lanes per cooperative group
#define GPB      16   // groups per 256-thread block (k_setup; 2 samples/group)
#define SGPB     16   // groups per 256-thread solver block
#define SBLK     256  // solver block threads
#define NQBLK    768  // solver blocks (3 resident/CU at 48KB LDS = all resident)

// ======================= TOOLCHAIN REGISTER-CAP MAPPING =====================
// __launch_bounds__(B, N) on this toolchain caps VGPRs at 256/N (NOT 512/N):
//   N=2 -> 128 (R4/R7 no-spill), N=3 -> 85 (R0: 84), N=4 -> 64 (R6 SPILL),
//   N=5 -> 51 (R5: 48, SPILL).  Any kernel with >64 live VGPRs MUST use N<=2.
// Spill tripwire in counters: FETCH/WRITE_SIZE >> ideal + low VALUBusy.
// ===========================================================================

typedef __attribute__((ext_vector_type(8))) short bf16x8;  // 8 bf16 (4 VGPRs)
typedef __attribute__((ext_vector_type(8))) unsigned short u16x8;
typedef __attribute__((ext_vector_type(4))) float f32x4;   // 4 fp32 acc

// wave-internal LDS ordering (groups live inside one wave; no block barrier
// inside the divergent solve loop).
__device__ __forceinline__ void wsync() {
    __builtin_amdgcn_wave_barrier();
    __threadfence_block();
    __builtin_amdgcn_wave_barrier();
}

__device__ __forceinline__ float sp_(float x) {
    return fmaxf(x, 0.f) + log1pf(expf(-fabsf(x)));
}
// fast softplus: __expf/__logf (rel err ~1e-6; negligible vs TOL / bf16 budget)
__device__ __forceinline__ float spf_(float x) {
    return fmaxf(x, 0.f) + __logf(1.f + __expf(-fabsf(x)));
}
__device__ __forceinline__ float sgn_(float d) {
    return (d > 0.f) ? 1.f : ((d < 0.f) ? -1.f : 0.f);
}
__device__ __forceinline__ unsigned short f2bf(float f) {   // RNE f32->bf16
    unsigned int u = __float_as_uint(f);
    u += 0x7FFFu + ((u >> 16) & 1u);
    return (unsigned short)(u >> 16);
}
__device__ __forceinline__ float bf2f(unsigned short u) {
    return __uint_as_float(((unsigned int)u) << 16);
}

// ---- swizzled per-wave LDS activation tiles (G4: XOR row bits into bank bits)
__device__ __forceinline__ void aw_st(unsigned short* aw, int row, int col, float v) {
    const int b = (row * 64 + col * 2) ^ ((row & 3) << 4);
    *(unsigned short*)((char*)aw + b) = f2bf(v);
}
__device__ __forceinline__ bf16x8 aw_ld(const unsigned short* aw, int row, int k) {
    const int b = (row * 64 + k * 2) ^ ((row & 3) << 4);
    return *(const bf16x8*)((const char*)aw + b);
}
__device__ __forceinline__ void hw_st(unsigned short* hw, int row, int col, float v) {
    const int b = (row * 256 + col * 2) ^ ((row & 7) << 4);
    *(unsigned short*)((char*)hw + b) = f2bf(v);
}
__device__ __forceinline__ bf16x8 hw_ld(const unsigned short* hw, int row, int k) {
    const int b = (row * 256 + k * 2) ^ ((row & 7) << 4);
    return *(const bf16x8*)((const char*)hw + b);
}

// ---------------------------------------------------------------------------
// paired V-ONLY eval (k_solve, secant solver): V(fxA*gA), V(fxB*gB), sharing
// all W2 loads from LDS.  fp32 h1 (R9 lesson: bf16-quantized h1 makes
// V(gamma) a step function with jumps >> TOL -> eval count ~2x).  Swizzled
// float2 layout: store (j<<4)|gl conflict-free; read group-uniform broadcast.
// w3 reads from global (2KB, L1-resident).
__device__ __forceinline__ void veval2_sec(
    const int gl, const float (&uA)[8], const float (&uB)[8],
    const float gA, const float gB,
    float2* h1q, const float n2A, const float n2B,
    const float (&b1v)[8], const float (&b2v)[8], const float (&d0c)[8],
    const unsigned short* w2L, const unsigned short* __restrict__ w3s,
    float& VA, float& VB)
{
    const int k0 = gl * 8;
#pragma unroll
    for (int j = 0; j < 8; ++j) {
        const float preA = fmaf(gA, uA[j], b1v[j]);
        const float preB = fmaf(gB, uB[j], b1v[j]);
        h1q[(j << 4) | gl] = make_float2(spf_(preA), spf_(preB));  // k = gl*8+j
    }
    wsync();
    float aA[8], aB[8];
#pragma unroll
    for (int j = 0; j < 8; ++j) { aA[j] = 0.f; aB[j] = 0.f; }
#pragma unroll 4
    for (int k = 0; k < HVD; ++k) {
        const float2 q = h1q[((k & 7) << 4) | (k >> 3)];   // uniform -> broadcast
        const u16x8 wv = *(const u16x8*)(w2L + k * HVD + k0);  // ds_read_b128
#pragma unroll
        for (int j = 0; j < 8; ++j) {
            const float w = bf2f(wv[j]);
            aA[j] = fmaf(q.x, w, aA[j]);
            aB[j] = fmaf(q.y, w, aB[j]);
        }
    }
    wsync();
    float oA[KVD], oB[KVD];
#pragma unroll
    for (int c = 0; c < KVD; ++c) { oA[c] = 0.f; oB[c] = 0.f; }
#pragma unroll
    for (int j = 0; j < 8; ++j) {
        const float h2A = spf_(aA[j] + b2v[j]);
        const float h2B = spf_(aB[j] + b2v[j]);
        const u16x8 w3v = *(const u16x8*)(w3s + (k0 + j) * KVD);   // global, L1
#pragma unroll
        for (int c = 0; c < 8; ++c) {
            const float w3 = bf2f(w3v[c]);
            oA[c] = fmaf(h2A, w3, oA[c]);
            oB[c] = fmaf(h2B, w3, oB[c]);
        }
    }
#pragma unroll
    for (int m = 1; m < G; m <<= 1) {
#pragma unroll
        for (int c = 0; c < KVD; ++c) {
            oA[c] += __shfl_xor(oA[c], m);
            oB[c] += __shfl_xor(oB[c], m);
        }
    }
    float vvA = 0.f, vvB = 0.f;
#pragma unroll
    for (int c = 0; c < KVD; ++c) {
        const float eA = oA[c] + d0c[c];
        const float eB = oB[c] + d0c[c];
        vvA = fmaf(eA, eA, vvA);
        vvB = fmaf(eB, eB, vvB);
    }
    VA = vvA + EPS_C * gA * gA * n2A;
    VB = vvB + EPS_C * gB * gB * n2B;
}

// ---- weight prep (+ h0 as block 32, parallelized) --------------------------
// R11: k_h0 folded in — it headed the stream as a 1-block latency-bound
// kernel; now it runs concurrently with the weight conversion.  h0 layer-2
// split 2 threads/col (64 k each), layer-3 16 chunks x 8 k (fp32 reassoc,
// ~1e-6 rel — negligible).
__global__ __launch_bounds__(256, 2) void k_wprep(
    const float* __restrict__ vW1, const float* __restrict__ vW2,
    const float* __restrict__ vW3,
    const float* __restrict__ vb1, const float* __restrict__ vb2,
    const float* __restrict__ vb3,
    unsigned short* __restrict__ w1b, unsigned short* __restrict__ w2b,
    unsigned short* __restrict__ w3b,
    unsigned short* __restrict__ w2s, unsigned short* __restrict__ w3s,
    float* __restrict__ h0g)
{
    if (blockIdx.x == 32) {          // ---- h0 = V-MLP(0) ----
        __shared__ float h1s[HVD];
        __shared__ float h2p[2][HVD];
        __shared__ float h2s[HVD];
        __shared__ float o3p[16][KVD + 1];
        const int t = threadIdx.x;
        if (t < HVD) h1s[t] = sp_(vb1[t]);
        __syncthreads();
        {
            const int j = t & 127, half = t >> 7;
            float a = half ? 0.f : vb2[j];
            const int kb = half * 64;
            for (int k = 0; k < 64; ++k)
                a = fmaf(h1s[kb + k], vW2[(kb + k) * HVD + j], a);
            h2p[half][j] = a;
        }
        __syncthreads();
        if (t < HVD) h2s[t] = sp_(h2p[0][t] + h2p[1][t]);
        __syncthreads();
        if (t < 128) {
            const int c = t & 7, ch = t >> 3;     // 16 chunks x 8 k
            float a = 0.f;
            for (int k = ch * 8; k < ch * 8 + 8; ++k)
                a = fmaf(h2s[k], vW3[k * KVD + c], a);
            o3p[ch][c] = a;
        }
        __syncthreads();
        if (t < KVD) {
            float acc = vb3[t];
            for (int ch = 0; ch < 16; ++ch) acc += o3p[ch][t];
            h0g[t] = acc;
        }
        return;
    }
    const int t = blockIdx.x * 256 + threadIdx.x;
    const int nth = 32 * 256;
    for (int i = t; i < HVD * NN; i += nth) {          // [128 col][32 k]
        const int col = i >> 5, k = i & 31;
        w1b[i] = f2bf(vW1[k * HVD + col]);
    }
    for (int i = t; i < HVD * HVD; i += nth) {         // [128 col][128 k]
        const int col = i >> 7, k = i & 127;
        w2b[i] = f2bf(vW2[k * HVD + col]);
    }
    for (int i = t; i < 16 * HVD; i += nth) {          // [16 col][128 k], cols 8..15 = 0
        const int c = i >> 7, k = i & 127;
        w3b[i] = (c < KVD) ? f2bf(vW3[k * KVD + c]) : (unsigned short)0;
    }
    for (int i = t; i < HVD * HVD; i += nth)           // [k][col] elementwise
        w2s[i] = f2bf(vW2[i]);
    for (int i = t; i < HVD * KVD; i += nth)           // [k][c] elementwise
        w3s[i] = f2bf(vW3[i]);
}

// ---- setup: f-net fp32 (spf_ softplus), V-net via bf16 MFMA ---------------
// R11: launch_bounds (256,2) — the old (256,4) capped VGPRs at 64 (=256/4)
// while acc2[8] alone is 32 VGPRs -> silent scratch spill since R1 (FETCH
// 4.5MB, VALUBusy 25% @ MfmaUtil 2%).  At 128 cap: 4 waves/SIMD, 4 blocks/CU
// (LDS 28KB x4 = 112KB), no spill.
__global__ __launch_bounds__(256, 2) void k_setup(
    const float* __restrict__ x_g,
    const float* __restrict__ fW1, const float* __restrict__ fb1,
    const float* __restrict__ fW2, const float* __restrict__ fb2,
    const float* __restrict__ fW3, const float* __restrict__ fb3,
    const float* __restrict__ vb1, const float* __restrict__ vb2,
    const float* __restrict__ vb3,
    const unsigned short* __restrict__ w1b,
    const unsigned short* __restrict__ w2b,
    const unsigned short* __restrict__ w3b,
    const float* __restrict__ h0g,
    float* __restrict__ out,
    int* __restrict__ cnt, int* __restrict__ list, float* __restrict__ tgt,
    float* __restrict__ vfb)
{
    __shared__ float2 xs[GPB][NN + 1];                       // 4.2 KB (f-net x)
    __shared__ float2 fh1[GPB][HFD + 1];                     // 3.3 KB (A,B pair)
    __shared__ float2 fh2[GPB][HFD + 1];                     // 3.3 KB
    __shared__ __align__(16) unsigned short abf[4][16 * 32]; // 4 KB  (Z rows bf16)
    __shared__ __align__(16) unsigned short hbf[4][16 * HVD];// 16 KB (h1/h2 reuse)
    __shared__ int wcnt[4];
    __shared__ int bbase;

    const int tid = threadIdx.x;
    const int gi = tid >> 4;          // group 0..15
    const int gl = tid & (G - 1);
    const int w  = tid >> 6;          // wave 0..3
    const int l  = tid & 63;
    const int q  = l >> 4;            // lane quad within wave (== gi & 3)
    const int cc = l & 15;
    const int sb = (blockIdx.x * GPB + gi) * 2;
    const int s0 = sb, s1 = sb + 1;
    unsigned short* aw = abf[w];
    unsigned short* hw = hbf[w];

    // ---- stage x (fp32 for f-net, bf16 rows for V A-operand) ----
    const float xa0 = x_g[(size_t)s0 * NN + gl];
    const float xa1 = x_g[(size_t)s0 * NN + gl + 16];
    const float xb0 = x_g[(size_t)s1 * NN + gl];
    const float xb1 = x_g[(size_t)s1 * NN + gl + 16];
    xs[gi][gl]      = make_float2(xa0, xb0);
    xs[gi][gl + 16] = make_float2(xa1, xb1);
    const int r0 = 4 * q;             // this group's base row in the wave tile
    aw_st(aw, r0,     gl,      xa0); aw_st(aw, r0,     gl + 16, xa1);
    aw_st(aw, r0 + 2, gl,      xb0); aw_st(aw, r0 + 2, gl + 16, xb1);
    wsync();

    // ---- f-net, both samples interleaved (fp32 fma, fast softplus) ----
    float fA0, fA1, fB0, fB1;
    for (int uu = gl; uu < HFD; uu += G) {
        float a0 = fb1[uu];
        float a1 = a0;
#pragma unroll
        for (int i = 0; i < NN; ++i) {
            const float2 xv2 = xs[gi][i];
            const float wv = fW1[i * HFD + uu];
            a0 = fmaf(xv2.x, wv, a0);
            a1 = fmaf(xv2.y, wv, a1);
        }
        fh1[gi][uu] = make_float2(spf_(a0), spf_(a1));
    }
    wsync();
    for (int uu = gl; uu < HFD; uu += G) {
        float a0 = fb2[uu];
        float a1 = a0;
#pragma unroll
        for (int i = 0; i < HFD; ++i) {
            const float2 h = fh1[gi][i];
            const float wv = fW2[i * HFD + uu];
            a0 = fmaf(h.x, wv, a0);
            a1 = fmaf(h.y, wv, a1);
        }
        fh2[gi][uu] = make_float2(spf_(a0), spf_(a1));
    }
    wsync();
    {
        float A0 = fb3[gl], A1 = fb3[gl + 16];
        float B0 = A0,      B1 = A1;
#pragma unroll
        for (int i = 0; i < HFD; ++i) {
            const float2 h = fh2[gi][i];
            const float wa = fW3[i * NN + gl];
            const float wb = fW3[i * NN + gl + 16];
            A0 = fmaf(h.x, wa, A0); A1 = fmaf(h.x, wb, A1);
            B0 = fmaf(h.y, wa, B0); B1 = fmaf(h.y, wb, B1);
        }
        out[(size_t)s0 * NN + gl]      = A0;
        out[(size_t)s0 * NN + gl + 16] = A1;
        out[(size_t)s1 * NN + gl]      = B0;
        out[(size_t)s1 * NN + gl + 16] = B1;
        aw_st(aw, r0 + 1, gl, A0); aw_st(aw, r0 + 1, gl + 16, A1);
        aw_st(aw, r0 + 3, gl, B0); aw_st(aw, r0 + 3, gl + 16, B1);
        fA0 = A0; fA1 = A1; fB0 = B0; fB1 = B1;
    }
    wsync();

    // ---- ||z||^2 per row (fp32 exact) ----
    float p0 = fmaf(xa0, xa0, xa1 * xa1);
    float p1 = fmaf(fA0, fA0, fA1 * fA1);
    float p2 = fmaf(xb0, xb0, xb1 * xb1);
    float p3 = fmaf(fB0, fB0, fB1 * fB1);
#pragma unroll
    for (int m = 1; m < G; m <<= 1) {
        p0 += __shfl_xor(p0, m); p1 += __shfl_xor(p1, m);
        p2 += __shfl_xor(p2, m); p3 += __shfl_xor(p3, m);
    }

    float b1v[8], b2v[8];
#pragma unroll
    for (int n = 0; n < 8; ++n) {
        b1v[n] = vb1[n * 16 + cc];    // col = n*16 + cc
        b2v[n] = vb2[n * 16 + cc];
    }

    const int kq = (l >> 4) * 8;      // this lane's k-offset within a K=32 chunk
    const f32x4 zf = {0.f, 0.f, 0.f, 0.f};

    // ---- V layer 1: u[16][128] = Z[16][32] @ W1  (8 MFMA, K=32 exact) ----
    const bf16x8 afr = aw_ld(aw, cc, kq);        // A: row=l&15, k=8*(l>>4)+j
    f32x4 acc1[8];
#pragma unroll
    for (int n = 0; n < 8; ++n) {
        const bf16x8 bfr = *(const bf16x8*)(w1b + (n * 16 + cc) * 32 + kq);
        acc1[n] = __builtin_amdgcn_mfma_f32_16x16x32_bf16(afr, bfr, zf, 0, 0, 0);
    }
    // h1 = softplus(u + b1) -> hbf (C layout: row=4q+r, col=n*16+cc)
#pragma unroll
    for (int n = 0; n < 8; ++n) {
#pragma unroll
        for (int r = 0; r < 4; ++r)
            hw_st(hw, r0 + r, n * 16 + cc, spf_(acc1[n][r] + b1v[n]));
    }
    wsync();

    // ---- V layer 2: a2[16][128] = H1 @ W2  (32 MFMA) ----
    f32x4 acc2[8];
#pragma unroll
    for (int n = 0; n < 8; ++n) acc2[n] = zf;
#pragma unroll
    for (int c = 0; c < 4; ++c) {
        const bf16x8 a2f = hw_ld(hw, cc, c * 32 + kq);
#pragma unroll
        for (int n = 0; n < 8; ++n) {
            const bf16x8 b2f = *(const bf16x8*)(w2b + (n * 16 + cc) * HVD + c * 32 + kq);
            acc2[n] = __builtin_amdgcn_mfma_f32_16x16x32_bf16(a2f, b2f, acc2[n], 0, 0, 0);
        }
    }
    wsync();   // all W2 A-reads done before overwriting hbf with h2
#pragma unroll
    for (int n = 0; n < 8; ++n) {
#pragma unroll
        for (int r = 0; r < 4; ++r)
            hw_st(hw, r0 + r, n * 16 + cc, spf_(acc2[n][r] + b2v[n]));
    }
    wsync();

    // ---- V layer 3: o[16][16] = H2 @ W3pad  (4 MFMA, cols 8..15 zero) ----
    f32x4 acc3 = zf;
#pragma unroll
    for (int c = 0; c < 4; ++c) {
        const bf16x8 a3f = hw_ld(hw, cc, c * 32 + kq);
        const bf16x8 b3f = *(const bf16x8*)(w3b + cc * HVD + c * 32 + kq);
        acc3 = __builtin_amdgcn_mfma_f32_16x16x32_bf16(a3f, b3f, acc3, 0, 0, 0);
    }

    // ---- finalize V per row; rows 4q+r belong to THIS group's samples ----
    const float d0 = (cc < KVD) ? (vb3[cc] - h0g[cc]) : 0.f;
    float s_[4];
#pragma unroll
    for (int r = 0; r < 4; ++r) {
        const float e = (cc < KVD) ? (acc3[r] + d0) : 0.f;  // zero pad lanes
        s_[r] = e * e;
    }
#pragma unroll
    for (int m = 1; m < G; m <<= 1) {
#pragma unroll
        for (int r = 0; r < 4; ++r) s_[r] += __shfl_xor(s_[r], m);
    }
    const float Vx0 = s_[0] + EPS_C * p0;
    const float Vf0 = s_[1] + EPS_C * p1;
    const float Vx1 = s_[2] + EPS_C * p2;
    const float Vf1 = s_[3] + EPS_C * p3;

    const float t0 = BETA_C * Vx0;
    const float t1 = BETA_C * Vx1;
    const bool act0 = (Vf0 - t0) > 0.f;        // group-uniform
    const bool act1 = (Vf1 - t1) > 0.f;

    const bool lead = (gl == 0 && act0) || (gl == 1 && act1);
    unsigned long long bal = __ballot(lead);
    const int lane = threadIdx.x & 63, wv = threadIdx.x >> 6;
    const int rank = __popcll(bal & ((1ull << lane) - 1ull));
    if (lane == 0) wcnt[wv] = __popcll(bal);
    __syncthreads();
    if (threadIdx.x == 0) {
        int tot = 0;
        for (int i = 0; i < 4; ++i) { int c = wcnt[i]; wcnt[i] = tot; tot += c; }
        bbase = atomicAdd(cnt, tot);
    }
    __syncthreads();
    if (lead) {
        const int p = bbase + wcnt[wv] + rank;
        list[p] = (gl == 0) ? s0 : s1;
        tgt[p]  = (gl == 0) ? t0 : t1;
        vfb[p]  = (gl == 0) ? Vf0 : Vf1;       // V(fhatx) — solver's V(1)
    }
}

// ---- solver: persistent groups, PAIRED samples, SAFEGUARDED SECANT --------
// R11: post-FORCE step alternates clamped false-position (superlinear on
// smooth V; clamp to [0.1,0.9] of bracket) with bisection (guaranteed >=2x
// contraction every 2 steps — preserves the R2 bounded-termination fix).
// Cuts the ~16-eval grind chains that form the low-occupancy tail.
__global__ __launch_bounds__(SBLK, 2) void k_solve(
    const float* __restrict__ vW1, const float* __restrict__ vb1,
    const unsigned short* __restrict__ w2s, const float* __restrict__ vb2,
    const unsigned short* __restrict__ w3s, const float* __restrict__ vb3,
    const float* __restrict__ h0g,
    float* __restrict__ out,
    const int* __restrict__ cnt, const int* __restrict__ list,
    const float* __restrict__ tgt, const float* __restrict__ vfb,
    int* __restrict__ qhead)
{
    __shared__ __align__(16) unsigned short w2L[HVD * HVD];  // 32 KB
    __shared__ __align__(8) float2 h1s[SGPB][HVD];           // 16 KB (fp32 pair)

    // ---- stage W2 to LDS (linear 16B copies; conflict-free reads) ----
    {
        const uint4* s2 = (const uint4*)w2s;
        uint4* d2 = (uint4*)w2L;
        for (int i = threadIdx.x; i < (HVD * HVD) / 8; i += SBLK) d2[i] = s2[i];
    }
    __syncthreads();   // only block-wide barrier; groups diverge after this

    const int gi = threadIdx.x >> 4;
    const int gl = threadIdx.x & (G - 1);
    const int n  = *cnt;
    float2* h1q = h1s[gi];
    const int lead = threadIdx.x & 48;   // group-lead LANE within the wave

    const int k0 = gl * 8;
    float b1v[8], b2v[8], d0c[8];
    {
        const float4 a = *(const float4*)(vb1 + k0);
        const float4 b = *(const float4*)(vb1 + k0 + 4);
        b1v[0]=a.x; b1v[1]=a.y; b1v[2]=a.z; b1v[3]=a.w;
        b1v[4]=b.x; b1v[5]=b.y; b1v[6]=b.z; b1v[7]=b.w;
        const float4 c = *(const float4*)(vb2 + k0);
        const float4 d = *(const float4*)(vb2 + k0 + 4);
        b2v[0]=c.x; b2v[1]=c.y; b2v[2]=c.z; b2v[3]=c.w;
        b2v[4]=d.x; b2v[5]=d.y; b2v[6]=d.z; b2v[7]=d.w;
#pragma unroll
        for (int cix = 0; cix < KVD; ++cix) d0c[cix] = vb3[cix] - h0g[cix];
    }

    int sA, sB; float tgA, tgB, fA0, fA1, fB0, fB1, n2A, n2B;
    float uA[8], uB[8];
    float gA, e1A, e2A, vA1, vA2, pgA, pvA;
    float gB, e1B, e2B, vB1, vB2, pgB, pvB;
    bool doneA, doneB;
    int itA, itB, obhA, obhB;

    auto grab = [&]() -> bool {
        int v = 0;
        if (gl == 0) v = atomicAdd(qhead, 2);
        v = __shfl(v, lead);
        if (v >= n) return false;
        const bool hasB = (v + 1) < n;
        sA = list[v]; tgA = tgt[v];
        const float vfA = vfb[v];
        float vfB;
        if (hasB) { sB = list[v + 1]; tgB = tgt[v + 1]; vfB = vfb[v + 1]; }
        else      { sB = sA;          tgB = tgA;        vfB = vfA; }
        fA0 = out[(size_t)sA * NN + gl];
        fA1 = out[(size_t)sA * NN + gl + 16];
        fB0 = out[(size_t)sB * NN + gl];
        fB1 = out[(size_t)sB * NN + gl + 16];
        // ||fx||^2 via group reduce (no LDS)
        float pa = fmaf(fA0, fA0, fA1 * fA1);
        float pb = fmaf(fB0, fB0, fB1 * fB1);
#pragma unroll
        for (int m = 1; m < G; m <<= 1) {
            pa += __shfl_xor(pa, m);
            pb += __shfl_xor(pb, m);
        }
        n2A = pa; n2B = pb;
        // u = fx @ vW1 cols k0..k0+7; fx broadcast via shfl (i unrolled ->
        // source operand is compile-time fA0/fA1)
#pragma unroll
        for (int j = 0; j < 8; ++j) { uA[j] = 0.f; uB[j] = 0.f; }
#pragma unroll
        for (int i = 0; i < NN; ++i) {
            const int src = lead + (i & 15);
            const float qx = __shfl((i < 16) ? fA0 : fA1, src);
            const float qy = __shfl((i < 16) ? fB0 : fB1, src);
            const float4 wa = *(const float4*)(vW1 + i * HVD + k0);
            const float4 wb = *(const float4*)(vW1 + i * HVD + k0 + 4);
            uA[0] = fmaf(qx, wa.x, uA[0]); uA[1] = fmaf(qx, wa.y, uA[1]);
            uA[2] = fmaf(qx, wa.z, uA[2]); uA[3] = fmaf(qx, wa.w, uA[3]);
            uA[4] = fmaf(qx, wb.x, uA[4]); uA[5] = fmaf(qx, wb.y, uA[5]);
            uA[6] = fmaf(qx, wb.z, uA[6]); uA[7] = fmaf(qx, wb.w, uA[7]);
            uB[0] = fmaf(qy, wa.x, uB[0]); uB[1] = fmaf(qy, wa.y, uB[1]);
            uB[2] = fmaf(qy, wa.z, uB[2]); uB[3] = fmaf(qy, wa.w, uB[3]);
            uB[4] = fmaf(qy, wb.x, uB[4]); uB[5] = fmaf(qy, wb.y, uB[5]);
            uB[6] = fmaf(qy, wb.z, uB[6]); uB[7] = fmaf(qy, wb.w, uB[7]);
        }
        // secant state: previous point = (1, vf) (known from k_setup)
        gA = sqrtf(tgA / vfA); e1A = 0.f; e2A = 1.f; vA1 = 0.f; vA2 = vfA;
        pgA = 1.f; pvA = vfA;
        gB = sqrtf(tgB / vfB); e1B = 0.f; e2B = 1.f; vB1 = 0.f; vB2 = vfB;
        pgB = 1.f; pvB = vfB;
        doneA = false; itA = 0; obhA = 0;
        doneB = !hasB; itB = 0; obhB = 0;
        return true;
    };
    if (!grab()) return;

    auto step = [&](bool& done, float& gamma, float& pg, float& pv,
                    float& e1, float& e2, float& v_e1, float& v_e2,
                    int& it, int& obh,
                    const float vp, const float target,
                    const int s, const float f0, const float f1) {
        if (done) return;
        // accept: at tolerance or bracket collapsed
        if (fabsf(vp - target) <= TOL_C || (e2 - e1) <= BRK_C) {
            out[(size_t)s * NN + gl]      = f0 * gamma;
            out[(size_t)s * NN + gl + 16] = f1 * gamma;
            done = true;
            return;
        }
        // ALWAYS contract the bracket with this eval.
        const float sa = sgn_(vp - target);
        const float s1 = sgn_(v_e1 - target);
        if (sa * s1 < 0.f) { e2 = gamma; v_e2 = vp; }
        else               { e1 = gamma; v_e1 = vp; }
        ++it;
        // secant proposal through (gamma, vp) and (pg, pv)
        const float newt = gamma - (vp - target) * (gamma - pg) / (vp - pv);
        pg = gamma; pv = vp;
        if (it < FORCE_C && newt >= e1 && newt <= e2) {   // NaN/inf fails -> below
            if (fabsf(newt - gamma) <= ACC_C) {
                // early accept: skip verification eval
                out[(size_t)s * NN + gl]      = f0 * newt;
                out[(size_t)s * NN + gl + 16] = f1 * newt;
                done = true;
                return;
            }
            gamma = newt;
        } else if (newt > e2 && e2 >= 1.0f) {
            // no-root band signature: root claimed above never-contracted e2=1
            if (++obh >= 2) {
                out[(size_t)s * NN + gl]      = f0;       // gamma = 1 exactly
                out[(size_t)s * NN + gl + 16] = f1;
                done = true;
                return;
            }
            gamma = 0.5f * (e1 + e2);                     // one confirming probe
        } else {
            // alternate clamped false-position / bisection: superlinear on
            // smooth V, still >=2x bracket contraction every 2 steps
            if (it & 1) {
                gamma = 0.5f * (e1 + e2);
            } else {
                const float fr0 = (target - v_e1) / (v_e2 - v_e1);  // in (0,1)
                const float fr = fminf(fmaxf(fr0, 0.1f), 0.9f);
                gamma = fmaf(fr, e2 - e1, e1);
            }
        }
        if (it >= MAXIT_C) {
            out[(size_t)s * NN + gl]      = f0 * gamma;
            out[(size_t)s * NN + gl + 16] = f1 * gamma;
            done = true;
        }
    };

    for (;;) {
        float vpA, vpB;
        veval2_sec(gl, uA, uB, gA, gB, h1q, n2A, n2B,
                   b1v, b2v, d0c, w2L, w3s, vpA, vpB);
        step(doneA, gA, pgA, pvA, e1A, e2A, vA1, vA2, itA, obhA, vpA, tgA, sA, fA0, fA1);
        step(doneB, gB, pgB, pvB, e1B, e2B, vB1, vB2, itB, obhB, vpB, tgB, sB, fB0, fB1);
        if (doneA && doneB) {
            if (!grab()) break;
        }
    }
}

extern "C" void kernel_launch(void* const* d_in, const int* in_sizes, int n_in,
                              void* d_out, int out_size, void* d_ws, size_t ws_size,
                              hipStream_t stream)
{
    const float* x   = (const float*)d_in[0];
    const float* fW1 = (const float*)d_in[1];
    const float* fb1 = (const float*)d_in[2];
    const float* fW2 = (const float*)d_in[3];
    const float* fb2 = (const float*)d_in[4];
    const float* fW3 = (const float*)d_in[5];
    const float* fb3 = (const float*)d_in[6];
    const float* vW1 = (const float*)d_in[7];
    const float* vb1 = (const float*)d_in[8];
    const float* vW2 = (const float*)d_in[9];
    const float* vb2 = (const float*)d_in[10];
    const float* vW3 = (const float*)d_in[11];
    const float* vb3 = (const float*)d_in[12];
    float* out = (float*)d_out;

    char* ws = (char*)d_ws;
    int*   cnt   = (int*)ws;                                 // 4 B
    int*   qhead = (int*)(ws + 4);                           // 4 B
    float* h0g   = (float*)(ws + 64);                        // 8 floats
    int*   list  = (int*)(ws + 128);                         // BN ints
    float* tgt   = (float*)(ws + 128 + (size_t)BN * 4);      // BN floats
    float* vfb   = (float*)(ws + 128 + (size_t)BN * 8);      // BN floats
    unsigned short* w1b = (unsigned short*)(ws + 128 + (size_t)BN * 12);  // 8 KB (16B-aligned)
    unsigned short* w2b = w1b + HVD * NN;                    // 32 KB
    unsigned short* w3b = w2b + HVD * HVD;                   // 4 KB
    unsigned short* w2s = w3b + 16 * HVD;                    // 32 KB (solver, [k][col])
    unsigned short* w3s = w2s + HVD * HVD;                   // 2 KB  (solver, [k][c])

    hipMemsetAsync(ws, 0, 8, stream);                        // cnt + qhead

    hipLaunchKernelGGL(k_wprep, dim3(33), dim3(256), 0, stream,
                       vW1, vW2, vW3, vb1, vb2, vb3,
                       w1b, w2b, w3b, w2s, w3s, h0g);

    hipLaunchKernelGGL(k_setup, dim3(BN / (GPB * 2)), dim3(256), 0, stream,
                       x, fW1, fb1, fW2, fb2, fW3, fb3,
                       vb1, vb2, vb3, w1b, w2b, w3b,
                       h0g, out, cnt, list, tgt, vfb);

    hipLaunchKernelGGL(k_solve, dim3(NQBLK), dim3(SBLK), 0, stream,
                       vW1, vb1, w2s, vb2, w3s, vb3,
                       h0g, out, cnt, list, tgt, vfb, qhead);
}